// Round 2
// baseline (529.523 us; speedup 1.0000x reference)
//
#include <hip/hip_runtime.h>
#include <hip/hip_bf16.h>
#include <math.h>

#define S_ 4
#define N_ 4096
#define M_ 4096
#define D_ 128
#define NEG_ (-1e30f)

typedef __bf16 bf16x8 __attribute__((ext_vector_type(8)));
typedef float f32x4 __attribute__((ext_vector_type(4)));

// RNE float -> bf16 bits (no NaN handling needed for this data)
__device__ __forceinline__ unsigned short f2bf(float f) {
    unsigned u = __float_as_uint(f);
    unsigned r = (u + 0x7FFFu + ((u >> 16) & 1u)) >> 16;
    return (unsigned short)r;
}

// ---------------- Phase 1: L2-normalize rows, write bf16 ----------------
// one wave per row of D_=128; lane handles 2 elements
__global__ void nrm_rows_kernel(const float* __restrict__ in,
                                unsigned short* __restrict__ out, int rows) {
    const int w = threadIdx.x >> 6;
    const int lane = threadIdx.x & 63;
    const int row = blockIdx.x * 4 + w;
    if (row >= rows) return;
    const float2 v = *reinterpret_cast<const float2*>(in + (size_t)row * D_ + lane * 2);
    float ss = v.x * v.x + v.y * v.y;
#pragma unroll
    for (int off = 1; off < 64; off <<= 1) ss += __shfl_xor(ss, off);
    const float scale = 1.0f / fmaxf(sqrtf(ss), 1e-12f);
    unsigned pack = (unsigned)f2bf(v.x * scale) | ((unsigned)f2bf(v.y * scale) << 16);
    *reinterpret_cast<unsigned*>(out + (size_t)row * D_ + lane * 2) = pack;
}

// ---------------- mask dtype detection ----------------
// If bool was uploaded as 1-byte, reading as int32 shows values > 1 (packed bytes).
__global__ void detect_mask_kernel(const unsigned* __restrict__ mask, int* __restrict__ flag) {
    int big = 0;
    for (int i = threadIdx.x; i < 4096; i += 64)
        if (mask[i] > 1u) big = 1;
    unsigned long long b = __ballot(big);
    if (threadIdx.x == 0) *flag = (b != 0ull) ? 1 : 0;  // 1 => uint8 bytes, 0 => int32
}

// ---------------- Phase 2: fused GEMM + masked/unmasked online logsumexp ----------------
// grid: S_ * (N_/32) blocks, 256 threads (4 waves).
// wave w: n-subtile = w&1 (16 anchors), m-half = w>>1 (M_/2 columns).
// MFMA computes T[m][n] (transposed) so each lane owns one n and 4 consecutive m.
__global__ __launch_bounds__(256) void infonce_main_kernel(
    const unsigned short* __restrict__ an, const unsigned short* __restrict__ rn,
    const void* __restrict__ maskp, const float* __restrict__ logtemp,
    const int* __restrict__ flag, float* __restrict__ accum) {

    const int bid = blockIdx.x;
    const int s = bid >> 7;            // N_/32 = 128 blocks per stem
    const int n_base = (bid & 127) * 32;
    const int tid = threadIdx.x;
    const int w = tid >> 6;
    const int lane = tid & 63;
    const int nsub = w & 1;
    const int mhalf = w >> 1;
    const int n16 = n_base + nsub * 16;
    const int lrow = lane & 15;        // n_local (MFMA col) / row-in-frag
    const int lgrp = lane >> 4;        // fragment k-group / output row group
    const float inv_temp = __expf(-logtemp[0]);
    const bool mask_is_byte = (*flag != 0);

    // art (B-operand) fragments: resident in registers for the whole M loop
    bf16x8 bfr[4];
    const unsigned short* abase = an + ((size_t)(s * N_ + n16 + lrow)) * D_ + lgrp * 8;
#pragma unroll
    for (int kc = 0; kc < 4; ++kc)
        bfr[kc] = *reinterpret_cast<const bf16x8*>(abase + kc * 32);

    float dmax = NEG_, dsum = 0.f, nmax = NEG_, nsum = 0.f;
    int npos = 0;

    const int m_begin = mhalf * (M_ / 2);
    const unsigned short* rbase = rn + ((size_t)(s * M_ + m_begin + lrow)) * D_ + lgrp * 8;
    const size_t mrow = ((size_t)s * N_ + (n16 + lrow)) * M_;  // this lane's mask row

    for (int mt = 0; mt < (M_ / 2) / 16; ++mt) {
        f32x4 acc = {0.f, 0.f, 0.f, 0.f};
        const unsigned short* rp = rbase + (size_t)mt * 16 * D_;
#pragma unroll
        for (int kc = 0; kc < 4; ++kc) {
            bf16x8 afr = *reinterpret_cast<const bf16x8*>(rp + kc * 32);
            acc = __builtin_amdgcn_mfma_f32_16x16x32_bf16(afr, bfr[kc], acc, 0, 0, 0);
        }
        const int m0 = m_begin + mt * 16 + lgrp * 4;
        int pm0, pm1, pm2, pm3;
        if (mask_is_byte) {
            const uchar4 mv = *reinterpret_cast<const uchar4*>(
                (const unsigned char*)maskp + mrow + m0);
            pm0 = mv.x; pm1 = mv.y; pm2 = mv.z; pm3 = mv.w;
        } else {
            const int4 mv = *reinterpret_cast<const int4*>((const int*)maskp + mrow + m0);
            pm0 = mv.x; pm1 = mv.y; pm2 = mv.z; pm3 = mv.w;
        }
        const float l0 = acc[0] * inv_temp, l1 = acc[1] * inv_temp;
        const float l2 = acc[2] * inv_temp, l3 = acc[3] * inv_temp;
        // den (all columns)
        float tmax = fmaxf(fmaxf(l0, l1), fmaxf(l2, l3));
        float nmx = fmaxf(dmax, tmax);
        dsum = dsum * __expf(dmax - nmx)
             + __expf(l0 - nmx) + __expf(l1 - nmx) + __expf(l2 - nmx) + __expf(l3 - nmx);
        dmax = nmx;
        // num (masked). Branchless: NEG_ entries contribute exp(-1e30)=0 once a real
        // max is seen; pre-max garbage is wiped by *exp(NEG_-real)=0. npos==0 anchors
        // are discarded by the validity test.
        const float s0 = pm0 ? l0 : NEG_, s1 = pm1 ? l1 : NEG_;
        const float s2 = pm2 ? l2 : NEG_, s3 = pm3 ? l3 : NEG_;
        float tmax2 = fmaxf(fmaxf(s0, s1), fmaxf(s2, s3));
        float nmx2 = fmaxf(nmax, tmax2);
        nsum = nsum * __expf(nmax - nmx2)
             + __expf(s0 - nmx2) + __expf(s1 - nmx2) + __expf(s2 - nmx2) + __expf(s3 - nmx2);
        nmax = nmx2;
        npos += (pm0 != 0) + (pm1 != 0) + (pm2 != 0) + (pm3 != 0);
    }

    // merge the 4 lane-groups (same n, different m subsets): xor 16, 32
#pragma unroll
    for (int off = 16; off < 64; off <<= 1) {
        float odm = __shfl_xor(dmax, off), ods = __shfl_xor(dsum, off);
        float onm = __shfl_xor(nmax, off), ons = __shfl_xor(nsum, off);
        int onp = __shfl_xor(npos, off);
        float nm = fmaxf(dmax, odm);
        dsum = dsum * __expf(dmax - nm) + ods * __expf(odm - nm);
        dmax = nm;
        float nm2 = fmaxf(nmax, onm);
        nsum = nsum * __expf(nmax - nm2) + ons * __expf(onm - nm2);
        nmax = nm2;
        npos += onp;
    }

    __shared__ float lds[4][16][5];
    if (lane < 16) {
        lds[w][lane][0] = dmax; lds[w][lane][1] = dsum;
        lds[w][lane][2] = nmax; lds[w][lane][3] = nsum;
        lds[w][lane][4] = (float)npos;
    }
    __syncthreads();

    if (w == 0) {
        const int nl = lane & 31;          // n_local 0..31 (lanes >=32 duplicate, zeroed)
        const int wsub = nl >> 4;          // 0 -> waves {0,2}, 1 -> waves {1,3}
        const int ni = nl & 15;
        float adm = lds[wsub][ni][0], ads = lds[wsub][ni][1];
        float anm = lds[wsub][ni][2], ans = lds[wsub][ni][3];
        float apc = lds[wsub][ni][4];
        float bdm = lds[wsub + 2][ni][0], bds = lds[wsub + 2][ni][1];
        float bnm = lds[wsub + 2][ni][2], bns = lds[wsub + 2][ni][3];
        float bpc = lds[wsub + 2][ni][4];
        float dm = fmaxf(adm, bdm);
        float ds = ads * __expf(adm - dm) + bds * __expf(bdm - dm);
        float nm = fmaxf(anm, bnm);
        float ns = ans * __expf(anm - nm) + bns * __expf(bnm - nm);
        int np = (int)(apc + bpc);
        bool valid = (np > 0) && (np < M_);
        float pa = valid ? ((dm + __logf(ds)) - (nm + __logf(ns))) : 0.f;
        float cv = valid ? 1.f : 0.f;
        if (lane >= 32) { pa = 0.f; cv = 0.f; }
#pragma unroll
        for (int off = 1; off < 64; off <<= 1) {
            pa += __shfl_xor(pa, off);
            cv += __shfl_xor(cv, off);
        }
        if (lane == 0) {
            atomicAdd(&accum[s * 2 + 0], pa);
            atomicAdd(&accum[s * 2 + 1], cv);
        }
    }
}

// ---------------- finalize ----------------
__global__ void finalize_kernel(const float* __restrict__ accum, float* __restrict__ out) {
    if (threadIdx.x == 0) {
        float total = 0.f;
        int scnt = 0;
        for (int s = 0; s < S_; ++s) {
            float sum = accum[s * 2 + 0];
            float cnt = accum[s * 2 + 1];
            float stem = sum / fmaxf(cnt, 1.f);
            if (cnt > 0.f) { total += stem; scnt++; }
        }
        out[0] = total / (float)(scnt > 0 ? scnt : 1);
    }
}

extern "C" void kernel_launch(void* const* d_in, const int* in_sizes, int n_in,
                              void* d_out, int out_size, void* d_ws, size_t ws_size,
                              hipStream_t stream) {
    const float* art = (const float*)d_in[0];
    const float* ref = (const float*)d_in[1];
    const void* mask = d_in[2];
    const float* lt = (const float*)d_in[3];
    float* out = (float*)d_out;

    char* ws = (char*)d_ws;
    unsigned short* an = (unsigned short*)ws;                              // 4 MB
    unsigned short* rn = (unsigned short*)(ws + (size_t)S_ * N_ * D_ * 2); // 4 MB
    float* accum = (float*)(ws + (size_t)S_ * N_ * D_ * 2 + (size_t)S_ * M_ * D_ * 2);
    int* flag = (int*)(accum + 2 * S_);

    hipMemsetAsync(accum, 0, 2 * S_ * sizeof(float), stream);
    nrm_rows_kernel<<<(S_ * N_) / 4, 256, 0, stream>>>(art, an, S_ * N_);
    nrm_rows_kernel<<<(S_ * M_) / 4, 256, 0, stream>>>(ref, rn, S_ * M_);
    detect_mask_kernel<<<1, 64, 0, stream>>>((const unsigned*)mask, flag);
    infonce_main_kernel<<<S_ * (N_ / 32), 256, 0, stream>>>(an, rn, mask, lt, flag, accum);
    finalize_kernel<<<1, 64, 0, stream>>>(accum, out);
}

// Round 3
// 470.294 us; speedup vs baseline: 1.1259x; 1.1259x over previous
//
#include <hip/hip_runtime.h>
#include <hip/hip_bf16.h>
#include <math.h>

#define S_ 4
#define N_ 4096
#define M_ 4096
#define D_ 128
#define NEG_ (-1e30f)
#define CH_ 4              // m-chunks per stem (grid parallelism knob)
#define MCH_ (M_ / CH_)    // 1024 m per chunk

typedef __bf16 bf16x8 __attribute__((ext_vector_type(8)));
typedef float f32x4 __attribute__((ext_vector_type(4)));

// RNE float -> bf16 bits
__device__ __forceinline__ unsigned short f2bf(float f) {
    unsigned u = __float_as_uint(f);
    unsigned r = (u + 0x7FFFu + ((u >> 16) & 1u)) >> 16;
    return (unsigned short)r;
}

// ---------------- Phase 1: L2-normalize art AND ref rows, write bf16 ----------------
// one wave per row of D_=128; lane handles 2 elements
__global__ void nrm_rows_kernel(const float* __restrict__ art, const float* __restrict__ ref,
                                unsigned short* __restrict__ an, unsigned short* __restrict__ rn) {
    const int w = threadIdx.x >> 6;
    const int lane = threadIdx.x & 63;
    const int row = blockIdx.x * 4 + w;             // 0 .. S_*(N_+M_)-1
    const bool is_art = row < S_ * N_;
    const float* src = is_art ? (art + (size_t)row * D_)
                              : (ref + (size_t)(row - S_ * N_) * D_);
    unsigned short* dst = is_art ? (an + (size_t)row * D_)
                                 : (rn + (size_t)(row - S_ * N_) * D_);
    const float2 v = *reinterpret_cast<const float2*>(src + lane * 2);
    float ss = v.x * v.x + v.y * v.y;
#pragma unroll
    for (int off = 1; off < 64; off <<= 1) ss += __shfl_xor(ss, off);
    const float scale = 1.0f / fmaxf(sqrtf(ss), 1e-12f);
    unsigned pack = (unsigned)f2bf(v.x * scale) | ((unsigned)f2bf(v.y * scale) << 16);
    *reinterpret_cast<unsigned*>(dst + lane * 2) = pack;
}

// ---------------- Phase 2: fused GEMM + masked/unmasked online logsumexp ----------------
// grid: 2048 blocks (CH_ chunks x S_ stems x 128 n-blocks), 256 threads (4 waves).
// XCD-bijective swizzle: consecutive 256-block runs (one (ch,s) rn chunk x2) per XCD.
// wave w: n-subtile = w&1 (16 anchors), m-sub = w>>1 (512 of the chunk's 1024 m).
// MFMA computes T[m][n] (transposed): lane owns one n (col), 4 consecutive m per acc.
// 2 m-tiles per iteration = 2 independent MFMA chains (ILP) + single merged LSE update.
__global__ __launch_bounds__(256, 6) void infonce_main_kernel(
    const unsigned short* __restrict__ an, const unsigned short* __restrict__ rn,
    const void* __restrict__ maskp, const float* __restrict__ logtemp,
    float4* __restrict__ part4, float* __restrict__ partn) {

    const int bid = blockIdx.x;
    const int swz = (bid & 7) * 256 + (bid >> 3);   // 2048 % 8 == 0 -> bijective
    const int ch = swz >> 9;                        // 0..3
    const int s = (swz >> 7) & 3;                   // 0..3
    const int nblk = swz & 127;                     // 0..127
    const int n_base = nblk * 32;

    const int tid = threadIdx.x;
    const int w = tid >> 6;
    const int lane = tid & 63;
    const int nsub = w & 1;
    const int msub = w >> 1;
    const int n16 = n_base + nsub * 16;
    const int lrow = lane & 15;        // MFMA col = anchor index in 16-group
    const int lgrp = lane >> 4;        // k-group / output row group
    const float inv_temp = __expf(-logtemp[0]);

    // inline mask dtype detection: byte-packed bools read as u32 show values >1
    const unsigned probe = ((const unsigned*)maskp)[lane];
    const bool mask_is_byte = (__ballot(probe > 1u) != 0ull);

    // art (B-operand) fragments: resident in registers for the whole loop
    bf16x8 bfr[4];
    const unsigned short* abase = an + ((size_t)(s * N_ + n16 + lrow)) * D_ + lgrp * 8;
#pragma unroll
    for (int kc = 0; kc < 4; ++kc)
        bfr[kc] = *reinterpret_cast<const bf16x8*>(abase + kc * 32);

    float dmax = NEG_, dsum = 0.f, nmax = NEG_, nsum = 0.f;
    int npos = 0;

    const int m_begin = ch * MCH_ + msub * (MCH_ / 2);   // 512 m's per wave
    const unsigned short* rbase = rn + ((size_t)(s * M_ + m_begin + lrow)) * D_ + lgrp * 8;
    const size_t mrow = ((size_t)(s * N_ + n16 + lrow)) * M_;

    for (int it = 0; it < (MCH_ / 2) / 32; ++it) {       // 16 iters x 2 tiles
        const int t0 = it * 2, t1 = t0 + 1;
        const int m0a = m_begin + t0 * 16 + lgrp * 4;
        const int m0b = m_begin + t1 * 16 + lgrp * 4;
        // mask loads first (longest latency: HBM stream)
        int pm[8];
        if (mask_is_byte) {
            const uchar4 ma = *reinterpret_cast<const uchar4*>((const unsigned char*)maskp + mrow + m0a);
            const uchar4 mb = *reinterpret_cast<const uchar4*>((const unsigned char*)maskp + mrow + m0b);
            pm[0] = ma.x; pm[1] = ma.y; pm[2] = ma.z; pm[3] = ma.w;
            pm[4] = mb.x; pm[5] = mb.y; pm[6] = mb.z; pm[7] = mb.w;
        } else {
            const int4 ma = *reinterpret_cast<const int4*>((const int*)maskp + mrow + m0a);
            const int4 mb = *reinterpret_cast<const int4*>((const int*)maskp + mrow + m0b);
            pm[0] = ma.x; pm[1] = ma.y; pm[2] = ma.z; pm[3] = ma.w;
            pm[4] = mb.x; pm[5] = mb.y; pm[6] = mb.z; pm[7] = mb.w;
        }
        // two independent MFMA chains
        f32x4 acc0 = {0.f, 0.f, 0.f, 0.f}, acc1 = {0.f, 0.f, 0.f, 0.f};
        const unsigned short* rp0 = rbase + (size_t)t0 * 16 * D_;
        const unsigned short* rp1 = rbase + (size_t)t1 * 16 * D_;
#pragma unroll
        for (int kc = 0; kc < 4; ++kc) {
            acc0 = __builtin_amdgcn_mfma_f32_16x16x32_bf16(
                *reinterpret_cast<const bf16x8*>(rp0 + kc * 32), bfr[kc], acc0, 0, 0, 0);
            acc1 = __builtin_amdgcn_mfma_f32_16x16x32_bf16(
                *reinterpret_cast<const bf16x8*>(rp1 + kc * 32), bfr[kc], acc1, 0, 0, 0);
        }
        float l[8];
#pragma unroll
        for (int i = 0; i < 4; ++i) { l[i] = acc0[i] * inv_temp; l[i + 4] = acc1[i] * inv_temp; }
        // den (all columns): one running update per 8 logits
        float tmax = fmaxf(fmaxf(fmaxf(l[0], l[1]), fmaxf(l[2], l[3])),
                           fmaxf(fmaxf(l[4], l[5]), fmaxf(l[6], l[7])));
        float nmx = fmaxf(dmax, tmax);
        float e = __expf(dmax - nmx) * dsum;
#pragma unroll
        for (int i = 0; i < 8; ++i) e += __expf(l[i] - nmx);
        dsum = e; dmax = nmx;
        // num (masked), branchless
        float sm[8];
#pragma unroll
        for (int i = 0; i < 8; ++i) sm[i] = pm[i] ? l[i] : NEG_;
        float tmax2 = fmaxf(fmaxf(fmaxf(sm[0], sm[1]), fmaxf(sm[2], sm[3])),
                            fmaxf(fmaxf(sm[4], sm[5]), fmaxf(sm[6], sm[7])));
        float nmx2 = fmaxf(nmax, tmax2);
        float e2 = __expf(nmax - nmx2) * nsum;
#pragma unroll
        for (int i = 0; i < 8; ++i) e2 += __expf(sm[i] - nmx2);
        nsum = e2; nmax = nmx2;
#pragma unroll
        for (int i = 0; i < 8; ++i) npos += (pm[i] != 0);
    }

    // merge the 4 lane-groups (same n, different m subsets): xor 16, 32
#pragma unroll
    for (int off = 16; off < 64; off <<= 1) {
        float odm = __shfl_xor(dmax, off), ods = __shfl_xor(dsum, off);
        float onm = __shfl_xor(nmax, off), ons = __shfl_xor(nsum, off);
        int onp = __shfl_xor(npos, off);
        float nm = fmaxf(dmax, odm);
        dsum = dsum * __expf(dmax - nm) + ods * __expf(odm - nm);
        dmax = nm;
        float nm2 = fmaxf(nmax, onm);
        nsum = nsum * __expf(nmax - nm2) + ons * __expf(onm - nm2);
        nmax = nm2;
        npos += onp;
    }

    __shared__ float lds[4][16][5];
    if (lane < 16) {
        lds[w][lane][0] = dmax; lds[w][lane][1] = dsum;
        lds[w][lane][2] = nmax; lds[w][lane][3] = nsum;
        lds[w][lane][4] = (float)npos;
    }
    __syncthreads();

    // merge msub halves (waves {0,2} and {1,3}) and write the (anchor, chunk) partial
    if (w == 0 && lane < 32) {
        const int wsub = lane >> 4;        // which n-sub
        const int ni = lane & 15;
        float adm = lds[wsub][ni][0], ads = lds[wsub][ni][1];
        float anm = lds[wsub][ni][2], ans = lds[wsub][ni][3];
        float apc = lds[wsub][ni][4];
        float bdm = lds[wsub + 2][ni][0], bds = lds[wsub + 2][ni][1];
        float bnm = lds[wsub + 2][ni][2], bns = lds[wsub + 2][ni][3];
        float bpc = lds[wsub + 2][ni][4];
        float dm = fmaxf(adm, bdm);
        float ds = ads * __expf(adm - dm) + bds * __expf(bdm - dm);
        float nm = fmaxf(anm, bnm);
        float ns = ans * __expf(anm - nm) + bns * __expf(bnm - nm);
        const int ag = s * N_ + n_base + wsub * 16 + ni;   // global anchor
        part4[ag * CH_ + ch] = make_float4(dm, ds, nm, ns);
        partn[ag * CH_ + ch] = apc + bpc;
    }
}

// ---------------- Phase 3: merge chunk partials, per-stem reduce ----------------
// 64 blocks x 256 threads, one thread per anchor; a block is always within one stem.
__global__ void reduce_kernel(const float4* __restrict__ part4, const float* __restrict__ partn,
                              float* __restrict__ accum) {
    const int a = blockIdx.x * 256 + threadIdx.x;   // 0..16383
    const int s = a >> 12;
    const int w = threadIdx.x >> 6;
    const int lane = threadIdx.x & 63;
    float dm = NEG_, ds = 0.f, nm = NEG_, ns = 0.f, np = 0.f;
#pragma unroll
    for (int ch = 0; ch < CH_; ++ch) {
        const float4 p = part4[a * CH_ + ch];
        const float pn = partn[a * CH_ + ch];
        float m2 = fmaxf(dm, p.x);
        ds = ds * __expf(dm - m2) + p.y * __expf(p.x - m2);
        dm = m2;
        float m3 = fmaxf(nm, p.z);
        ns = ns * __expf(nm - m3) + p.w * __expf(p.z - m3);
        nm = m3;
        np += pn;
    }
    const int npi = (int)np;
    const bool valid = (npi > 0) && (npi < M_);
    float pa = valid ? ((dm + __logf(ds)) - (nm + __logf(ns))) : 0.f;
    float cv = valid ? 1.f : 0.f;
#pragma unroll
    for (int off = 1; off < 64; off <<= 1) {
        pa += __shfl_xor(pa, off);
        cv += __shfl_xor(cv, off);
    }
    __shared__ float sp[4], sc[4];
    if (lane == 0) { sp[w] = pa; sc[w] = cv; }
    __syncthreads();
    if (threadIdx.x == 0) {
        atomicAdd(&accum[s * 2 + 0], sp[0] + sp[1] + sp[2] + sp[3]);
        atomicAdd(&accum[s * 2 + 1], sc[0] + sc[1] + sc[2] + sc[3]);
    }
}

// ---------------- finalize ----------------
__global__ void finalize_kernel(const float* __restrict__ accum, float* __restrict__ out) {
    if (threadIdx.x == 0) {
        float total = 0.f;
        int scnt = 0;
        for (int s = 0; s < S_; ++s) {
            float sum = accum[s * 2 + 0];
            float cnt = accum[s * 2 + 1];
            float stem = sum / fmaxf(cnt, 1.f);
            if (cnt > 0.f) { total += stem; scnt++; }
        }
        out[0] = total / (float)(scnt > 0 ? scnt : 1);
    }
}

extern "C" void kernel_launch(void* const* d_in, const int* in_sizes, int n_in,
                              void* d_out, int out_size, void* d_ws, size_t ws_size,
                              hipStream_t stream) {
    const float* art = (const float*)d_in[0];
    const float* ref = (const float*)d_in[1];
    const void* mask = d_in[2];
    const float* lt = (const float*)d_in[3];
    float* out = (float*)d_out;

    char* ws = (char*)d_ws;
    unsigned short* an = (unsigned short*)ws;                                  // 4 MB
    unsigned short* rn = (unsigned short*)(ws + (size_t)4194304);              // 4 MB
    float4* part4 = (float4*)(ws + (size_t)8388608);                           // 1 MB
    float* partn = (float*)(ws + (size_t)9437184);                             // 256 KB
    float* accum = (float*)(ws + (size_t)9699328);                             // 32 B

    hipMemsetAsync(accum, 0, 2 * S_ * sizeof(float), stream);
    nrm_rows_kernel<<<(S_ * (N_ + M_)) / 4, 256, 0, stream>>>(art, ref, an, rn);
    infonce_main_kernel<<<S_ * (N_ / 32) * CH_, 256, 0, stream>>>(an, rn, mask, lt, part4, partn);
    reduce_kernel<<<(S_ * N_) / 256, 256, 0, stream>>>(part4, partn, accum);
    finalize_kernel<<<1, 64, 0, stream>>>(accum, out);
}

// Round 4
// 461.189 us; speedup vs baseline: 1.1482x; 1.0197x over previous
//
#include <hip/hip_runtime.h>
#include <hip/hip_bf16.h>
#include <math.h>

#define S_ 4
#define N_ 4096
#define M_ 4096
#define D_ 128
#define NEG_ (-1e30f)
#define CH_ 4              // m-chunks per stem
#define MCH_ (M_ / CH_)    // 1024 m per chunk
#define LN2_ 0.69314718055994531f
#define LOG2E_ 1.44269504088896340f

typedef __bf16 bf16x8 __attribute__((ext_vector_type(8)));
typedef float f32x4 __attribute__((ext_vector_type(4)));

// RNE float -> bf16 bits
__device__ __forceinline__ unsigned short f2bf(float f) {
    unsigned u = __float_as_uint(f);
    unsigned r = (u + 0x7FFFu + ((u >> 16) & 1u)) >> 16;
    return (unsigned short)r;
}

// ---------------- Phase 1: L2-normalize art AND ref rows, write bf16 ----------------
__global__ void nrm_rows_kernel(const float* __restrict__ art, const float* __restrict__ ref,
                                unsigned short* __restrict__ an, unsigned short* __restrict__ rn) {
    const int w = threadIdx.x >> 6;
    const int lane = threadIdx.x & 63;
    const int row = blockIdx.x * 4 + w;             // 0 .. S_*(N_+M_)-1
    const bool is_art = row < S_ * N_;
    const float* src = is_art ? (art + (size_t)row * D_)
                              : (ref + (size_t)(row - S_ * N_) * D_);
    unsigned short* dst = is_art ? (an + (size_t)row * D_)
                                 : (rn + (size_t)(row - S_ * N_) * D_);
    const float2 v = *reinterpret_cast<const float2*>(src + lane * 2);
    float ss = v.x * v.x + v.y * v.y;
#pragma unroll
    for (int off = 1; off < 64; off <<= 1) ss += __shfl_xor(ss, off);
    const float scale = 1.0f / fmaxf(sqrtf(ss), 1e-12f);
    unsigned pack = (unsigned)f2bf(v.x * scale) | ((unsigned)f2bf(v.y * scale) << 16);
    *reinterpret_cast<unsigned*>(dst + lane * 2) = pack;
}

// ---------------- hot loop: templated on mask dtype (branch hoisted out) ----------------
// Per iteration: 64 m = 4 16x16 tiles. All mask + rn loads issued up front,
// 4 independent MFMA chains, base-2 shared-max online LSE (den & num share the max).
template <bool BYTE>
__device__ __forceinline__ void lse_loop(
    const unsigned short* __restrict__ rbase, const void* __restrict__ maskp,
    size_t melt0, const bf16x8* __restrict__ bfr, float scale2,
    float& dmax, float& dsum, float& nsum, float& npf) {
#pragma unroll 2
    for (int it = 0; it < (MCH_ / 2) / 64; ++it) {   // 8 iterations
        // ---- mask loads first (HBM stream = longest latency) ----
        float fpm[16];
#pragma unroll
        for (int t = 0; t < 4; ++t) {
            if (BYTE) {
                const uchar4 mv = *reinterpret_cast<const uchar4*>(
                    (const unsigned char*)maskp + melt0 + it * 64 + t * 16);
                fpm[t * 4 + 0] = (float)mv.x; fpm[t * 4 + 1] = (float)mv.y;
                fpm[t * 4 + 2] = (float)mv.z; fpm[t * 4 + 3] = (float)mv.w;
            } else {
                const int4 mv = *reinterpret_cast<const int4*>(
                    (const int*)maskp + melt0 + it * 64 + t * 16);
                fpm[t * 4 + 0] = (float)mv.x; fpm[t * 4 + 1] = (float)mv.y;
                fpm[t * 4 + 2] = (float)mv.z; fpm[t * 4 + 3] = (float)mv.w;
            }
        }
        // ---- 4 independent MFMA chains ----
        f32x4 acc0 = {0.f, 0.f, 0.f, 0.f}, acc1 = {0.f, 0.f, 0.f, 0.f};
        f32x4 acc2 = {0.f, 0.f, 0.f, 0.f}, acc3 = {0.f, 0.f, 0.f, 0.f};
        const unsigned short* rp = rbase + (size_t)it * 64 * D_;
#pragma unroll
        for (int kc = 0; kc < 4; ++kc) {
            acc0 = __builtin_amdgcn_mfma_f32_16x16x32_bf16(
                *reinterpret_cast<const bf16x8*>(rp + 0 * 16 * D_ + kc * 32), bfr[kc], acc0, 0, 0, 0);
            acc1 = __builtin_amdgcn_mfma_f32_16x16x32_bf16(
                *reinterpret_cast<const bf16x8*>(rp + 1 * 16 * D_ + kc * 32), bfr[kc], acc1, 0, 0, 0);
            acc2 = __builtin_amdgcn_mfma_f32_16x16x32_bf16(
                *reinterpret_cast<const bf16x8*>(rp + 2 * 16 * D_ + kc * 32), bfr[kc], acc2, 0, 0, 0);
            acc3 = __builtin_amdgcn_mfma_f32_16x16x32_bf16(
                *reinterpret_cast<const bf16x8*>(rp + 3 * 16 * D_ + kc * 32), bfr[kc], acc3, 0, 0, 0);
        }
        // ---- base-2 logits ----
        float l[16];
#pragma unroll
        for (int i = 0; i < 4; ++i) {
            l[i]      = acc0[i] * scale2;  l[4 + i]  = acc1[i] * scale2;
            l[8 + i]  = acc2[i] * scale2;  l[12 + i] = acc3[i] * scale2;
        }
        // max tree (depth 4)
        float a0 = fmaxf(l[0], l[1]),  a1 = fmaxf(l[2], l[3]);
        float a2 = fmaxf(l[4], l[5]),  a3 = fmaxf(l[6], l[7]);
        float a4 = fmaxf(l[8], l[9]),  a5 = fmaxf(l[10], l[11]);
        float a6 = fmaxf(l[12], l[13]), a7 = fmaxf(l[14], l[15]);
        float b0 = fmaxf(a0, a1), b1 = fmaxf(a2, a3), b2 = fmaxf(a4, a5), b3 = fmaxf(a6, a7);
        float tmax = fmaxf(fmaxf(b0, b1), fmaxf(b2, b3));
        const float nmx = fmaxf(dmax, tmax);
        const float r = exp2f(dmax - nmx);
        float e[16];
#pragma unroll
        for (int i = 0; i < 16; ++i) e[i] = exp2f(l[i] - nmx);
        // den sum tree
        float s0 = (e[0] + e[1]) + (e[2] + e[3]), s1 = (e[4] + e[5]) + (e[6] + e[7]);
        float s2 = (e[8] + e[9]) + (e[10] + e[11]), s3 = (e[12] + e[13]) + (e[14] + e[15]);
        dsum = dsum * r + ((s0 + s1) + (s2 + s3));
        // num: fma chains (4 partials)
        float p0 = fpm[0] * e[0], p1 = fpm[1] * e[1], p2 = fpm[2] * e[2], p3 = fpm[3] * e[3];
#pragma unroll
        for (int i = 4; i < 16; i += 4) {
            p0 = fmaf(fpm[i], e[i], p0);     p1 = fmaf(fpm[i + 1], e[i + 1], p1);
            p2 = fmaf(fpm[i + 2], e[i + 2], p2); p3 = fmaf(fpm[i + 3], e[i + 3], p3);
        }
        nsum = nsum * r + ((p0 + p1) + (p2 + p3));
        // positive count
        float q0 = (fpm[0] + fpm[1]) + (fpm[2] + fpm[3]), q1 = (fpm[4] + fpm[5]) + (fpm[6] + fpm[7]);
        float q2 = (fpm[8] + fpm[9]) + (fpm[10] + fpm[11]), q3 = (fpm[12] + fpm[13]) + (fpm[14] + fpm[15]);
        npf += ((q0 + q1) + (q2 + q3));
        dmax = nmx;
    }
}

// ---------------- Phase 2: fused GEMM + masked/unmasked online logsumexp ----------------
// grid 2048 blocks (CH_ x S_ x 128 n-blocks), 256 threads. XCD-bijective swizzle.
// wave w: n-subtile = w&1, m-sub = w>>1. Transposed MFMA: lane owns 1 anchor col, 4 m rows.
__global__ __launch_bounds__(256, 4) void infonce_main_kernel(
    const unsigned short* __restrict__ an, const unsigned short* __restrict__ rn,
    const void* __restrict__ maskp, const float* __restrict__ logtemp,
    float4* __restrict__ part4) {

    const int bid = blockIdx.x;
    const int swz = (bid & 7) * 256 + (bid >> 3);   // 2048 % 8 == 0 -> bijective
    const int ch = swz >> 9;
    const int s = (swz >> 7) & 3;
    const int nblk = swz & 127;
    const int n_base = nblk * 32;

    const int tid = threadIdx.x;
    const int w = tid >> 6;
    const int lane = tid & 63;
    const int nsub = w & 1;
    const int msub = w >> 1;
    const int n16 = n_base + nsub * 16;
    const int lrow = lane & 15;
    const int lgrp = lane >> 4;
    const float scale2 = __expf(-logtemp[0]) * LOG2E_;   // 1/(temp*ln2)

    // mask dtype detection (byte-packed bools read as u32 show values >1)
    const unsigned probe = ((const unsigned*)maskp)[lane];
    const bool mask_is_byte = (__ballot(probe > 1u) != 0ull);

    // art fragments resident in registers
    bf16x8 bfr[4];
    const unsigned short* abase = an + ((size_t)(s * N_ + n16 + lrow)) * D_ + lgrp * 8;
#pragma unroll
    for (int kc = 0; kc < 4; ++kc)
        bfr[kc] = *reinterpret_cast<const bf16x8*>(abase + kc * 32);

    const int m_begin = ch * MCH_ + msub * (MCH_ / 2);
    const unsigned short* rbase = rn + ((size_t)(s * M_ + m_begin + lrow)) * D_ + lgrp * 8;
    const size_t melt0 = ((size_t)(s * N_ + n16 + lrow)) * M_ + m_begin + lgrp * 4;

    float dmax = NEG_, dsum = 0.f, nsum = 0.f, npf = 0.f;
    if (mask_is_byte) lse_loop<true >(rbase, maskp, melt0, bfr, scale2, dmax, dsum, nsum, npf);
    else              lse_loop<false>(rbase, maskp, melt0, bfr, scale2, dmax, dsum, nsum, npf);

    // merge the 4 lane-groups (same anchor, different m): xor 16, 32
#pragma unroll
    for (int off = 16; off < 64; off <<= 1) {
        float odm = __shfl_xor(dmax, off), ods = __shfl_xor(dsum, off);
        float ons = __shfl_xor(nsum, off), onp = __shfl_xor(npf, off);
        float nm = fmaxf(dmax, odm);
        float ra = exp2f(dmax - nm), rb = exp2f(odm - nm);
        dsum = dsum * ra + ods * rb;
        nsum = nsum * ra + ons * rb;
        npf += onp;
        dmax = nm;
    }

    __shared__ float4 lds4[4][16];
    if (lane < 16) lds4[w][lane] = make_float4(dmax, dsum, nsum, npf);
    __syncthreads();

    // merge msub halves (waves {0,2},{1,3}); write (anchor, chunk) partial
    if (w == 0 && lane < 32) {
        const int wsub = lane >> 4;
        const int ni = lane & 15;
        const float4 A = lds4[wsub][ni];
        const float4 B = lds4[wsub + 2][ni];
        const float nm = fmaxf(A.x, B.x);
        const float ra = exp2f(A.x - nm), rb = exp2f(B.x - nm);
        const float ds = A.y * ra + B.y * rb;
        const float ns = A.z * ra + B.z * rb;
        const float np = A.w + B.w;
        const int ag = s * N_ + n_base + wsub * 16 + ni;
        part4[ag * CH_ + ch] = make_float4(nm, ds, ns, np);
    }
}

// ---------------- Phase 3: merge chunk partials -> per-block (pa,cnt) partial ----------------
__global__ void reduce_kernel(const float4* __restrict__ part4, float2* __restrict__ bpart) {
    const int a = blockIdx.x * 256 + threadIdx.x;   // anchor
    const int w = threadIdx.x >> 6;
    const int lane = threadIdx.x & 63;
    float dm = NEG_, ds = 0.f, ns = 0.f, npf = 0.f;
#pragma unroll
    for (int ch = 0; ch < CH_; ++ch) {
        const float4 p = part4[a * CH_ + ch];
        const float m2 = fmaxf(dm, p.x);
        const float ra = exp2f(dm - m2), rb = exp2f(p.x - m2);
        ds = ds * ra + p.y * rb;
        ns = ns * ra + p.z * rb;
        npf += p.w;
        dm = m2;
    }
    const bool valid = (npf > 0.5f) && (npf < (float)M_ - 0.5f);
    float pa = valid ? LN2_ * (log2f(ds) - log2f(ns)) : 0.f;
    float cv = valid ? 1.f : 0.f;
#pragma unroll
    for (int off = 1; off < 64; off <<= 1) {
        pa += __shfl_xor(pa, off);
        cv += __shfl_xor(cv, off);
    }
    __shared__ float sp[4], sc[4];
    if (lane == 0) { sp[w] = pa; sc[w] = cv; }
    __syncthreads();
    if (threadIdx.x == 0)
        bpart[blockIdx.x] = make_float2(sp[0] + sp[1] + sp[2] + sp[3],
                                        sc[0] + sc[1] + sc[2] + sc[3]);
}

// ---------------- Phase 4: finalize (64 block-partials, 16 per stem) ----------------
__global__ void finalize_kernel(const float2* __restrict__ bpart, float* __restrict__ out) {
    const int t = threadIdx.x;   // 64 threads
    const float2 v = bpart[t];
    float pa = v.x, cv = v.y;
#pragma unroll
    for (int off = 1; off < 16; off <<= 1) {
        pa += __shfl_xor(pa, off);
        cv += __shfl_xor(cv, off);
    }
    const float p0 = __shfl(pa, 0),  c0 = __shfl(cv, 0);
    const float p1 = __shfl(pa, 16), c1 = __shfl(cv, 16);
    const float p2 = __shfl(pa, 32), c2 = __shfl(cv, 32);
    const float p3 = __shfl(pa, 48), c3 = __shfl(cv, 48);
    if (t == 0) {
        float total = 0.f;
        int scnt = 0;
        const float ps[4] = {p0, p1, p2, p3};
        const float cs[4] = {c0, c1, c2, c3};
        for (int s = 0; s < S_; ++s) {
            const float stem = ps[s] / fmaxf(cs[s], 1.f);
            if (cs[s] > 0.f) { total += stem; scnt++; }
        }
        out[0] = total / (float)(scnt > 0 ? scnt : 1);
    }
}

extern "C" void kernel_launch(void* const* d_in, const int* in_sizes, int n_in,
                              void* d_out, int out_size, void* d_ws, size_t ws_size,
                              hipStream_t stream) {
    const float* art = (const float*)d_in[0];
    const float* ref = (const float*)d_in[1];
    const void* mask = d_in[2];
    const float* lt = (const float*)d_in[3];
    float* out = (float*)d_out;

    char* ws = (char*)d_ws;
    unsigned short* an = (unsigned short*)ws;                      // 4 MB
    unsigned short* rn = (unsigned short*)(ws + (size_t)4194304);  // 4 MB
    float4* part4 = (float4*)(ws + (size_t)8388608);               // 1 MB
    float2* bpart = (float2*)(ws + (size_t)9437184);               // 512 B

    nrm_rows_kernel<<<(S_ * (N_ + M_)) / 4, 256, 0, stream>>>(art, ref, an, rn);
    infonce_main_kernel<<<S_ * (N_ / 32) * CH_, 256, 0, stream>>>(an, rn, mask, lt, part4);
    reduce_kernel<<<(S_ * N_) / 256, 256, 0, stream>>>(part4, bpart);
    finalize_kernel<<<1, 64, 0, stream>>>(bpart, out);
}